// Round 5
// baseline (236.642 us; speedup 1.0000x reference)
//
#include <hip/hip_runtime.h>
#include <hip/hip_bf16.h>

typedef short v8s __attribute__((ext_vector_type(8)));
typedef short v4s __attribute__((ext_vector_type(4)));
typedef float v4f __attribute__((ext_vector_type(4)));

#define BS 4
#define SEQ 2048
#define DMODEL 768
#define HEADS 12
#define GROUPS 2
#define DK 64
#define LOG2E 1.4426950408889634f

static __device__ __forceinline__ short f2bs(float f) {
    __hip_bfloat16 h = __float2bfloat16(f);
    return *reinterpret_cast<short*>(&h);
}

static __device__ __forceinline__ float fast_exp2(float x) {
#if __has_builtin(__builtin_amdgcn_exp2f)
    return __builtin_amdgcn_exp2f(x);
#else
    return __expf(x * 0.6931471805599453f);
#endif
}

// Async global->LDS, 16B per lane. LDS dest is WAVE-UNIFORM base; lane i's
// 16B lands at base + i*16 (m97 semantics).
static __device__ __forceinline__ void gld16(const short* g, short* l) {
    __builtin_amdgcn_global_load_lds(
        (__attribute__((address_space(1))) void*)(g),
        (__attribute__((address_space(3))) void*)(l), 16, 0, 0);
}

struct alignas(8) s4pack { short a, b, c, d; };

#define FENCE() asm volatile("" ::: "memory")
#define WAIT_VM0() asm volatile("s_waitcnt vmcnt(0)" ::: "memory")
#define WAIT_LGKM0() asm volatile("s_waitcnt lgkmcnt(0)" ::: "memory")
#define WAIT_VM0_LGKM0() asm volatile("s_waitcnt vmcnt(0) lgkmcnt(0)" ::: "memory")
#define BARRIER() do { FENCE(); __builtin_amdgcn_s_barrier(); FENCE(); } while (0)

// ---------------------------------------------------------------------------
// prep: merged convert_q (blocks 0..1535) + weight transpose (1536..2879).
// wtrans compact: z0/z1 = 576 blocks each, z2/z3 = 96 each (N=128).
// ---------------------------------------------------------------------------
__global__ __launch_bounds__(256) void prep(
    const float* __restrict__ q,
    const float* __restrict__ Wq, const float* __restrict__ Wk,
    const float* __restrict__ Wv, const float* __restrict__ Wo,
    short* __restrict__ qbf,
    short* __restrict__ WqT, short* __restrict__ WkT,
    short* __restrict__ WvT, short* __restrict__ WoT)
{
    __shared__ float tt[32][33];
    const int blk = blockIdx.x;

    if (blk < 1536) {
        const size_t base = (size_t)blk * 4096;
#pragma unroll
        for (int r = 0; r < 4; ++r) {
            const size_t i = base + r * 1024 + threadIdx.x * 4;
            const float4 a = *reinterpret_cast<const float4*>(q + i);
            s4pack p{f2bs(a.x), f2bs(a.y), f2bs(a.z), f2bs(a.w)};
            *reinterpret_cast<s4pack*>(qbf + i) = p;
        }
        return;
    }

    int r0 = blk - 1536;
    int z, bx, by;
    if (r0 < 576)       { z = 0; bx = r0 % 24; by = r0 / 24; }
    else if (r0 < 1152) { z = 1; r0 -= 576;  bx = r0 % 24; by = r0 / 24; }
    else if (r0 < 1248) { z = 2; r0 -= 1152; bx = r0 % 4;  by = r0 / 4; }
    else                { z = 3; r0 -= 1248; bx = r0 % 4;  by = r0 / 4; }

    const float* W;
    short* WT;
    int N;
    if (z == 0)      { W = Wq; WT = WqT; N = 768; }
    else if (z == 1) { W = Wo; WT = WoT; N = 768; }
    else if (z == 2) { W = Wk; WT = WkT; N = 128; }
    else             { W = Wv; WT = WvT; N = 128; }
    const int n0 = bx * 32, k0 = by * 32;

    const int lx = threadIdx.x & 31, ly = threadIdx.x >> 5;
#pragma unroll
    for (int r = 0; r < 4; ++r)
        tt[ly + r * 8][lx] = W[(size_t)(k0 + ly + r * 8) * N + n0 + lx];
    __syncthreads();
#pragma unroll
    for (int r = 0; r < 4; ++r)
        WT[(size_t)(n0 + ly + r * 8) * DMODEL + k0 + lx] = f2bs(tt[lx][ly + r * 8]);
}

// ---------------------------------------------------------------------------
// Merged Q/K/V projection. grid 1280 = 256 groups x {3 Q blocks + 2 KV}.
// Q: BM=64,BN=128,BK=64 from bf16 qbf via gld16; KV: BM=32 from fp32 via
// reg-stage. R2-proven single-barrier dbuf loop (stage t+1 -> compute t ->
// vmcnt(0) drain -> barrier). Epilogues use MFMA operand symmetry to get
// register-contiguous output columns -> 8B vector stores:
//   Q/K: mfma(bf,af) => 4 regs = 4 consecutive d  -> v4s store
//   V:   mfma(af,bf) => 4 regs = 4 consecutive s -> 4 consecutive s2 -> v4s
// ---------------------------------------------------------------------------
__global__ __launch_bounds__(256) void proj_qkv(
    const short* __restrict__ qbf, const float* __restrict__ kin,
    const float* __restrict__ vin,
    const short* __restrict__ WqT, const short* __restrict__ WkT,
    const short* __restrict__ WvT,
    const float* __restrict__ bq, const float* __restrict__ bk,
    const float* __restrict__ bv,
    short* __restrict__ Qp, short* __restrict__ Kp, short* __restrict__ Vt)
{
    __shared__ short lA[2][64 * 64];
    __shared__ short lB[2][128 * 64];

    const int blk   = blockIdx.x;
    const int group = blk / 5;
    const int pos   = blk - group * 5;

    const int tid  = threadIdx.x;
    const int lane = tid & 63;
    const int wid  = tid >> 6;
    const int l16  = lane & 15;
    const int quad = lane >> 4;

    // gld16 chunk: 1KB = 8 rows x 128B. Lane i lands at (row=c*8+(i>>3),
    // granule=i&7); fetch global granule (i&7)^(i>>3) so LDS[row][g] holds
    // global[row][g ^ (row&7)].
    const int crow = lane >> 3;
    const int ccol = ((lane & 7) ^ crow) << 3;

    if (pos < 3) {
        // ----------------- Q path -----------------
        const int qidx = group * 3 + pos;
        const int y  = qidx >> 7;
        const int bm = qidx & 127;
        const short* WT = WqT + (size_t)y * 128 * DMODEL;
        const int wm = wid & 1;
        const int wn = wid >> 1;

        v4f acc[2][4];
#pragma unroll
        for (int i = 0; i < 2; ++i)
#pragma unroll
            for (int j = 0; j < 4; ++j) acc[i][j] = (v4f){0.f, 0.f, 0.f, 0.f};

        const short* Abase = qbf + (size_t)bm * 64 * DMODEL;

        auto stage = [&](int kt, int pb) {
#pragma unroll
            for (int c = wid; c < 8; c += 4)
                gld16(Abase + (size_t)(c * 8 + crow) * DMODEL + kt * 64 + ccol, &lA[pb][c * 512]);
#pragma unroll
            for (int c = wid; c < 16; c += 4)
                gld16(WT + (size_t)(c * 8 + crow) * DMODEL + kt * 64 + ccol, &lB[pb][c * 512]);
        };
        auto compute = [&](int cur) {
#pragma unroll
            for (int kk = 0; kk < 2; ++kk) {
                const int fcol = (((kk << 2) + quad) ^ (l16 & 7)) << 3;
                v8s af[2], bf[4];
#pragma unroll
                for (int i = 0; i < 2; ++i)
                    af[i] = *reinterpret_cast<const v8s*>(&lA[cur][(wm * 32 + i * 16 + l16) * 64 + fcol]);
#pragma unroll
                for (int j = 0; j < 4; ++j)
                    bf[j] = *reinterpret_cast<const v8s*>(&lB[cur][(wn * 64 + j * 16 + l16) * 64 + fcol]);
                __builtin_amdgcn_s_setprio(1);
#pragma unroll
                for (int i = 0; i < 2; ++i)
#pragma unroll
                    for (int j = 0; j < 4; ++j)
                        acc[i][j] = __builtin_amdgcn_mfma_f32_16x16x32_bf16(bf[j], af[i], acc[i][j], 0, 0, 0);
                __builtin_amdgcn_s_setprio(0);
            }
        };

        stage(0, 0);
        WAIT_VM0();
        BARRIER();
        for (int kt = 0; kt < 12; ++kt) {
            const int cur = kt & 1;
            if (kt < 11) stage(kt + 1, cur ^ 1);
            compute(cur);
            WAIT_VM0();
            BARRIER();
        }

        // epilogue: col=lane&15 = s (af idx); row=quad*4+reg = output col d
#pragma unroll
        for (int i = 0; i < 2; ++i) {
            const int s = bm * 64 + wm * 32 + i * 16 + l16;
            const int b = s >> 11, srow = s & 2047;
#pragma unroll
            for (int j = 0; j < 4; ++j) {
                const int C = y * 128 + wn * 64 + j * 16 + quad * 4;
                const int h = C >> 6, d = C & 63;
                const float4 bb = *reinterpret_cast<const float4*>(&bq[C]);
                v4s p;
#pragma unroll
                for (int reg = 0; reg < 4; ++reg)
                    p[reg] = f2bs((acc[i][j][reg] + (&bb.x)[reg]) * LOG2E);
                *reinterpret_cast<v4s*>(
                    &Qp[((size_t)(b * HEADS + h) * SEQ + srow) * DK + d]) = p;
            }
        }
    } else {
        // ----------------- K/V path -----------------
        const int kvidx = group * 2 + (pos - 3);
        const int yv = kvidx >> 8;          // 0=K 1=V
        const int bm = kvidx & 255;
        const float* A = yv ? vin : kin;
        const short* WT = yv ? WvT : WkT;

        v4f acc[2][2];
#pragma unroll
        for (int i = 0; i < 2; ++i)
#pragma unroll
            for (int j = 0; j < 2; ++j) acc[i][j] = (v4f){0.f, 0.f, 0.f, 0.f};

        float4 areg[2];

        auto loadA = [&](int kt) {
#pragma unroll
            for (int r = 0; r < 2; ++r) {
                const int f4 = tid + 256 * r;
                const int row = f4 >> 4;
                const int q4 = f4 & 15;
                areg[r] = *reinterpret_cast<const float4*>(
                    A + (size_t)(bm * 32 + row) * DMODEL + kt * 64 + q4 * 4);
            }
        };
        auto writeA = [&](int pb) {
#pragma unroll
            for (int r = 0; r < 2; ++r) {
                const int f4 = tid + 256 * r;
                const int row = f4 >> 4;
                const int q4 = f4 & 15;
                const int gran = q4 >> 1, half = q4 & 1;
                const int scol = ((gran ^ (row & 7)) << 3) + (half << 2);
                s4pack p{f2bs(areg[r].x), f2bs(areg[r].y), f2bs(areg[r].z), f2bs(areg[r].w)};
                *reinterpret_cast<s4pack*>(&lA[pb][row * 64 + scol]) = p;
            }
        };
        auto stageB = [&](int kt, int pb) {
#pragma unroll
            for (int c = wid; c < 16; c += 4)
                gld16(WT + (size_t)(c * 8 + crow) * DMODEL + kt * 64 + ccol, &lB[pb][c * 512]);
        };
        auto compute = [&](int cur) {
#pragma unroll
            for (int kk = 0; kk < 2; ++kk) {
                const int fcol = (((kk << 2) + quad) ^ (l16 & 7)) << 3;
                v8s af[2], bf[2];
#pragma unroll
                for (int i = 0; i < 2; ++i)
                    af[i] = *reinterpret_cast<const v8s*>(&lA[cur][(i * 16 + l16) * 64 + fcol]);
#pragma unroll
                for (int j = 0; j < 2; ++j)
                    bf[j] = *reinterpret_cast<const v8s*>(&lB[cur][(wid * 32 + j * 16 + l16) * 64 + fcol]);
                __builtin_amdgcn_s_setprio(1);
#pragma unroll
                for (int i = 0; i < 2; ++i)
#pragma unroll
                    for (int j = 0; j < 2; ++j) {
                        if (yv == 0)
                            acc[i][j] = __builtin_amdgcn_mfma_f32_16x16x32_bf16(bf[j], af[i], acc[i][j], 0, 0, 0);
                        else
                            acc[i][j] = __builtin_amdgcn_mfma_f32_16x16x32_bf16(af[i], bf[j], acc[i][j], 0, 0, 0);
                    }
                __builtin_amdgcn_s_setprio(0);
            }
        };

        loadA(0);
        writeA(0);
        stageB(0, 0);
        WAIT_VM0_LGKM0();
        BARRIER();
        for (int kt = 0; kt < 12; ++kt) {
            const int cur = kt & 1;
            if (kt < 11) { loadA(kt + 1); stageB(kt + 1, cur ^ 1); }
            compute(cur);
            if (kt < 11) writeA(cur ^ 1);
            WAIT_VM0_LGKM0();
            BARRIER();
        }

        if (yv == 0) {
            // K: swapped -> 4 regs = 4 consecutive d at fixed s
#pragma unroll
            for (int i = 0; i < 2; ++i) {
                const int s = bm * 32 + i * 16 + l16;
                const int b = s >> 11, srow = s & 2047;
#pragma unroll
                for (int j = 0; j < 2; ++j) {
                    const int Cl = wid * 32 + j * 16 + quad * 4;
                    const int g = Cl >> 6, d = Cl & 63;
                    const float4 bb = *reinterpret_cast<const float4*>(&bk[Cl]);
                    v4s p;
#pragma unroll
                    for (int reg = 0; reg < 4; ++reg)
                        p[reg] = f2bs(acc[i][j][reg] + (&bb.x)[reg]);
                    *reinterpret_cast<v4s*>(
                        &Kp[((size_t)(b * GROUPS + g) * SEQ + srow) * DK + d]) = p;
                }
            }
        } else {
            // V: non-swapped -> 4 regs = 4 consecutive s -> consecutive s2
#pragma unroll
            for (int j = 0; j < 2; ++j) {
                const int Cl = wid * 32 + j * 16 + l16;
                const int g = Cl >> 6, d = Cl & 63;
                const float bvv = bv[Cl];
#pragma unroll
                for (int i = 0; i < 2; ++i) {
                    const int s = bm * 32 + i * 16 + quad * 4;   // reg=0 base
                    const int b = s >> 11, s0 = s & 2047;
                    const int s2 = (s0 & ~63) | (s0 & 0x23) | ((s0 & 0x0C) << 1) | ((s0 & 0x10) >> 2);
                    v4s p;
#pragma unroll
                    for (int reg = 0; reg < 4; ++reg)
                        p[reg] = f2bs(acc[i][j][reg] + bvv);
                    *reinterpret_cast<v4s*>(
                        &Vt[((size_t)(b * GROUPS + g) * DK + d) * SEQ + s2]) = p;
                }
            }
        }
    }
}

// ---------------------------------------------------------------------------
// Flash attention: R1/R4 measured-best structure (66.8us): 256 thr / 4 waves
// / mi=2, QBLK=128, padded LDS, T14 async-STAGE split, T5 setprio.
// ---------------------------------------------------------------------------
__global__ __launch_bounds__(256) void attn_kernel(
    const short* __restrict__ Qp, const short* __restrict__ Kp,
    const short* __restrict__ Vt, short* __restrict__ Oat)
{
    const int LSK = 72;
    const int LSV = 136;
    __shared__ short lK[128 * 72];
    __shared__ short lV[64 * 136];

    const int qt = blockIdx.x, h = blockIdx.y, b = blockIdx.z;
    const int g = h & 1;
    const int tid  = threadIdx.x;
    const int lane = tid & 63;
    const int wid  = tid >> 6;
    const int l16  = lane & 15;
    const int quad = lane >> 4;

    v8s qf[2][2];
#pragma unroll
    for (int mi = 0; mi < 2; ++mi) {
        const size_t qbase =
            ((size_t)(b * HEADS + h) * SEQ + qt * 128 + wid * 32 + mi * 16 + l16) * DK;
        qf[mi][0] = *reinterpret_cast<const v8s*>(Qp + qbase + quad * 8);
        qf[mi][1] = *reinterpret_cast<const v8s*>(Qp + qbase + quad * 8 + 32);
    }

    const size_t kbase = (size_t)(b * GROUPS + g) * SEQ * DK;
    const size_t vbase = (size_t)(b * GROUPS + g) * DK * SEQ;

    const short one = (short)0x3F80;
    const v8s ones8 = {one, one, one, one, one, one, one, one};

    v4f oacc[2][5];
#pragma unroll
    for (int mi = 0; mi < 2; ++mi)
#pragma unroll
        for (int n = 0; n < 5; ++n) oacc[mi][n] = (v4f){0.f, 0.f, 0.f, 0.f};

    v8s kreg[4], vreg[4];

    auto issue_loads = [&](int kt) {
#pragma unroll
        for (int r = 0; r < 4; ++r) {
            const int idx = tid + 256 * r;
            const int rowK = idx >> 3, cK = (idx & 7) << 3;
            kreg[r] = *reinterpret_cast<const v8s*>(
                Kp + kbase + (size_t)(kt * 128 + rowK) * DK + cK);
            const int rowV = idx >> 4, cV = (idx & 15) << 3;
            vreg[r] = *reinterpret_cast<const v8s*>(
                Vt + vbase + (size_t)rowV * SEQ + kt * 128 + cV);
        }
    };
    auto write_lds = [&]() {
#pragma unroll
        for (int r = 0; r < 4; ++r) {
            const int idx = tid + 256 * r;
            const int rowK = idx >> 3, cK = (idx & 7) << 3;
            *reinterpret_cast<v8s*>(&lK[rowK * LSK + cK]) = kreg[r];
            const int rowV = idx >> 4, cV = (idx & 15) << 3;
            *reinterpret_cast<v8s*>(&lV[rowV * LSV + cV]) = vreg[r];
        }
    };

    issue_loads(0);
    for (int kt = 0; kt < 16; ++kt) {
        if (kt) BARRIER();            // readers of tile kt-1 done (no vmcnt drain)
        write_lds();                  // consumes kreg/vreg (compiler vmcnt waits)
        if (kt < 15) issue_loads(kt + 1);  // in flight across barrier + compute
        WAIT_LGKM0();                 // ds_writes visible before barrier
        BARRIER();

#pragma unroll
        for (int kt2 = 0; kt2 < 2; ++kt2) {
            v4s pp[2][4];
#pragma unroll
            for (int j = 0; j < 4; ++j) {
                const v8s kf0 = *reinterpret_cast<const v8s*>(
                    &lK[(kt2 * 64 + j * 16 + l16) * LSK + quad * 8]);
                const v8s kf1 = *reinterpret_cast<const v8s*>(
                    &lK[(kt2 * 64 + j * 16 + l16) * LSK + quad * 8 + 32]);
#pragma unroll
                for (int mi = 0; mi < 2; ++mi) {
                    v4f z = (v4f){0.f, 0.f, 0.f, 0.f};
                    __builtin_amdgcn_s_setprio(1);
                    z = __builtin_amdgcn_mfma_f32_16x16x32_bf16(kf0, qf[mi][0], z, 0, 0, 0);
                    z = __builtin_amdgcn_mfma_f32_16x16x32_bf16(kf1, qf[mi][1], z, 0, 0, 0);
                    __builtin_amdgcn_s_setprio(0);
                    v4s p;
#pragma unroll
                    for (int reg = 0; reg < 4; ++reg) p[reg] = f2bs(fast_exp2(z[reg]));
                    pp[mi][j] = p;
                }
            }

#pragma unroll
            for (int cj = 0; cj < 2; ++cj) {
                v8s pf[2];
#pragma unroll
                for (int mi = 0; mi < 2; ++mi)
                    pf[mi] = __builtin_shufflevector(pp[mi][2 * cj], pp[mi][2 * cj + 1],
                                                     0, 1, 2, 3, 4, 5, 6, 7);
                __builtin_amdgcn_s_setprio(1);
#pragma unroll
                for (int n = 0; n < 4; ++n) {
                    const v8s vf = *reinterpret_cast<const v8s*>(
                        &lV[(n * 16 + l16) * LSV + kt2 * 64 + cj * 32 + quad * 8]);
#pragma unroll
                    for (int mi = 0; mi < 2; ++mi)
                        oacc[mi][n] = __builtin_amdgcn_mfma_f32_16x16x32_bf16(pf[mi], vf, oacc[mi][n], 0, 0, 0);
                }
#pragma unroll
                for (int mi = 0; mi < 2; ++mi)
                    oacc[mi][4] = __builtin_amdgcn_mfma_f32_16x16x32_bf16(pf[mi], ones8, oacc[mi][4], 0, 0, 0);
                __builtin_amdgcn_s_setprio(0);
            }
        }
    }

#pragma unroll
    for (int mi = 0; mi < 2; ++mi) {
        float rdiv[4];
#pragma unroll
        for (int reg = 0; reg < 4; ++reg)
            rdiv[reg] = __builtin_amdgcn_rcpf(oacc[mi][4][reg]);
#pragma unroll
        for (int n = 0; n < 4; ++n)
#pragma unroll
            for (int reg = 0; reg < 4; ++reg) {
                const int qrow = qt * 128 + wid * 32 + mi * 16 + quad * 4 + reg;
                Oat[(size_t)(b * SEQ + qrow) * DMODEL + h * 64 + n * 16 + l16] =
                    f2bs(oacc[mi][n][reg] * rdiv[reg]);
            }
    }
}

// ---------------------------------------------------------------------------
// Output GEMM: BM=64, BN=128, BK=64, dbuf, R2 single-barrier loop, swizzle.
// Swapped-operand MFMA -> float4 epilogue stores. grid (128, 6). out fp32.
// ---------------------------------------------------------------------------
__global__ __launch_bounds__(256) void out_gemm(
    const short* __restrict__ A, const short* __restrict__ WT,
    const float* __restrict__ bias, float* __restrict__ out)
{
    __shared__ short lA[2][64 * 64];
    __shared__ short lB[2][128 * 64];

    const int tid  = threadIdx.x;
    const int lane = tid & 63;
    const int wid  = tid >> 6;
    const int l16  = lane & 15;
    const int quad = lane >> 4;
    const int wm   = wid & 1;
    const int wn   = wid >> 1;
    const int bm   = blockIdx.x;
    const int bn   = blockIdx.y;

    v4f acc[2][4];
#pragma unroll
    for (int i = 0; i < 2; ++i)
#pragma unroll
        for (int j = 0; j < 4; ++j) acc[i][j] = (v4f){0.f, 0.f, 0.f, 0.f};

    const int crow = lane >> 3;
    const int ccol = ((lane & 7) ^ crow) << 3;
    const short* Abase = A + (size_t)bm * 64 * DMODEL;
    const short* Bbase = WT + (size_t)bn * 128 * DMODEL;

    auto stage = [&](int kt, int pb) {
#pragma unroll
        for (int c = wid; c < 8; c += 4)
            gld16(Abase + (size_t)(c * 8 + crow) * DMODEL + kt * 64 + ccol, &lA[pb][c * 512]);
#pragma unroll
        for (int c = wid; c < 16; c += 4)
            gld16(Bbase + (size_t)(c * 8 + crow) * DMODEL + kt * 64 + ccol, &lB[pb][c * 512]);
    };
    auto compute = [&](int cur) {
#pragma unroll
        for (int kk = 0; kk < 2; ++kk) {
            const int fcol = (((kk << 2) + quad) ^ (l16 & 7)) << 3;
            v8s af[2], bf[4];
#pragma unroll
            for (int i = 0; i < 2; ++i)
                af[i] = *reinterpret_cast<const v8s*>(&lA[cur][(wm * 32 + i * 16 + l16) * 64 + fcol]);
#pragma unroll
            for (int j = 0; j < 4; ++j)
                bf[j] = *reinterpret_cast<const v8s*>(&lB[cur][(wn * 64 + j * 16 + l16) * 64 + fcol]);
            __builtin_amdgcn_s_setprio(1);
#pragma unroll
            for (int i = 0; i < 2; ++i)
#pragma unroll
                for (int j = 0; j < 4; ++j)
                    acc[i][j] = __builtin_amdgcn_mfma_f32_16x16x32_bf16(bf[j], af[i], acc[i][j], 0, 0, 0);
            __builtin_amdgcn_s_setprio(0);
        }
    };

    stage(0, 0);
    WAIT_VM0();
    BARRIER();
    for (int kt = 0; kt < 12; ++kt) {
        const int cur = kt & 1;
        if (kt < 11) stage(kt + 1, cur ^ 1);
        compute(cur);
        WAIT_VM0();
        BARRIER();
    }

    // epilogue: col=lane&15 = R row; row=quad*4+reg = C col -> float4 store
#pragma unroll
    for (int i = 0; i < 2; ++i) {
        const int R = bm * 64 + wm * 32 + i * 16 + l16;
#pragma unroll
        for (int j = 0; j < 4; ++j) {
            const int C = bn * 128 + wn * 64 + j * 16 + quad * 4;
            const float4 bb = *reinterpret_cast<const float4*>(&bias[C]);
            float4 o;
#pragma unroll
            for (int reg = 0; reg < 4; ++reg)
                (&o.x)[reg] = acc[i][j][reg] + (&bb.x)[reg];
            *reinterpret_cast<float4*>(&out[(size_t)R * DMODEL + C]) = o;
        }
    }
}

extern "C" void kernel_launch(void* const* d_in, const int* in_sizes, int n_in,
                              void* d_out, int out_size, void* d_ws, size_t ws_size,
                              hipStream_t stream) {
    const float* q  = (const float*)d_in[0];
    const float* k  = (const float*)d_in[1];
    const float* v  = (const float*)d_in[2];
    const float* Wq = (const float*)d_in[3];
    const float* bq = (const float*)d_in[4];
    const float* Wk = (const float*)d_in[5];
    const float* bk = (const float*)d_in[6];
    const float* Wv = (const float*)d_in[7];
    const float* bv = (const float*)d_in[8];
    const float* Wo = (const float*)d_in[9];
    const float* bo = (const float*)d_in[10];

    short* WqT = (short*)d_ws;                              // 589824
    short* WkT = WqT + 589824;                              // 98304
    short* WvT = WkT + 98304;                               // 98304
    short* WoT = WvT + 98304;                               // 589824
    short* qbf = WoT + 589824;                              // 6291456
    short* Qp  = qbf + 6291456;                             // [b,h,s,d]  6291456
    short* Kp  = Qp + (size_t)BS * HEADS * SEQ * DK;        // [b,g,s,d]  1048576
    short* Vt  = Kp + (size_t)BS * GROUPS * SEQ * DK;       // [b,g,d,s_perm] 1048576
    short* Oat = Vt + (size_t)BS * GROUPS * SEQ * DK;       // [b,s,h*d]  6291456

    prep<<<2880, 256, 0, stream>>>(q, Wq, Wk, Wv, Wo, qbf, WqT, WkT, WvT, WoT);
    proj_qkv<<<1280, 256, 0, stream>>>(qbf, k, v, WqT, WkT, WvT,
                                       bq, bk, bv, Qp, Kp, Vt);
    attn_kernel<<<dim3(16, HEADS, BS), 256, 0, stream>>>(Qp, Kp, Vt, Oat);
    out_gemm<<<dim3(128, 6), 256, 0, stream>>>(Oat, WoT, bo, (float*)d_out);
}

// Round 6
// 231.097 us; speedup vs baseline: 1.0240x; 1.0240x over previous
//
#include <hip/hip_runtime.h>
#include <hip/hip_bf16.h>

typedef short v8s __attribute__((ext_vector_type(8)));
typedef short v4s __attribute__((ext_vector_type(4)));
typedef float v4f __attribute__((ext_vector_type(4)));

#define BS 4
#define SEQ 2048
#define DMODEL 768
#define HEADS 12
#define GROUPS 2
#define DK 64
#define LOG2E 1.4426950408889634f

static __device__ __forceinline__ short f2bs(float f) {
    __hip_bfloat16 h = __float2bfloat16(f);
    return *reinterpret_cast<short*>(&h);
}

static __device__ __forceinline__ float fast_exp2(float x) {
#if __has_builtin(__builtin_amdgcn_exp2f)
    return __builtin_amdgcn_exp2f(x);
#else
    return __expf(x * 0.6931471805599453f);
#endif
}

// Async global->LDS, 16B per lane. LDS dest is WAVE-UNIFORM base; lane i's
// 16B lands at base + i*16 (m97 semantics).
static __device__ __forceinline__ void gld16(const short* g, short* l) {
    __builtin_amdgcn_global_load_lds(
        (__attribute__((address_space(1))) void*)(g),
        (__attribute__((address_space(3))) void*)(l), 16, 0, 0);
}

struct alignas(8) s4pack { short a, b, c, d; };

#define FENCE() asm volatile("" ::: "memory")
#define WAIT_VM0() asm volatile("s_waitcnt vmcnt(0)" ::: "memory")
#define WAIT_LGKM0() asm volatile("s_waitcnt lgkmcnt(0)" ::: "memory")
#define WAIT_VM0_LGKM0() asm volatile("s_waitcnt vmcnt(0) lgkmcnt(0)" ::: "memory")
#define BARRIER() do { FENCE(); __builtin_amdgcn_s_barrier(); FENCE(); } while (0)

// ---------------------------------------------------------------------------
// prep: merged convert_q (blocks 0..1535) + weight transpose (1536..2879).
// ---------------------------------------------------------------------------
__global__ __launch_bounds__(256) void prep(
    const float* __restrict__ q,
    const float* __restrict__ Wq, const float* __restrict__ Wk,
    const float* __restrict__ Wv, const float* __restrict__ Wo,
    short* __restrict__ qbf,
    short* __restrict__ WqT, short* __restrict__ WkT,
    short* __restrict__ WvT, short* __restrict__ WoT)
{
    __shared__ float tt[32][33];
    const int blk = blockIdx.x;

    if (blk < 1536) {
        const size_t base = (size_t)blk * 4096;
#pragma unroll
        for (int r = 0; r < 4; ++r) {
            const size_t i = base + r * 1024 + threadIdx.x * 4;
            const float4 a = *reinterpret_cast<const float4*>(q + i);
            s4pack p{f2bs(a.x), f2bs(a.y), f2bs(a.z), f2bs(a.w)};
            *reinterpret_cast<s4pack*>(qbf + i) = p;
        }
        return;
    }

    int r0 = blk - 1536;
    int z, bx, by;
    if (r0 < 576)       { z = 0; bx = r0 % 24; by = r0 / 24; }
    else if (r0 < 1152) { z = 1; r0 -= 576;  bx = r0 % 24; by = r0 / 24; }
    else if (r0 < 1248) { z = 2; r0 -= 1152; bx = r0 % 4;  by = r0 / 4; }
    else                { z = 3; r0 -= 1248; bx = r0 % 4;  by = r0 / 4; }

    const float* W;
    short* WT;
    int N;
    if (z == 0)      { W = Wq; WT = WqT; N = 768; }
    else if (z == 1) { W = Wo; WT = WoT; N = 768; }
    else if (z == 2) { W = Wk; WT = WkT; N = 128; }
    else             { W = Wv; WT = WvT; N = 128; }
    const int n0 = bx * 32, k0 = by * 32;

    const int lx = threadIdx.x & 31, ly = threadIdx.x >> 5;
#pragma unroll
    for (int r = 0; r < 4; ++r)
        tt[ly + r * 8][lx] = W[(size_t)(k0 + ly + r * 8) * N + n0 + lx];
    __syncthreads();
#pragma unroll
    for (int r = 0; r < 4; ++r)
        WT[(size_t)(n0 + ly + r * 8) * DMODEL + k0 + lx] = f2bs(tt[lx][ly + r * 8]);
}

// ---------------------------------------------------------------------------
// Merged Q/K/V projection, XCD-chunked remap (T1): hardware round-robins
// blockIdx%8 over XCDs, so xcd=d&7, idx=d>>3. Each XCD gets 96 Q blocks in
// bm-major order (o=bm*6+y: the 6 N-slices sharing one A-panel are adjacent
// in time on ONE XCD -> A hits L2 5/6 times) + 64 KV blocks (pipe mixing).
// Loop bodies identical to R5 (measured-stable).
// ---------------------------------------------------------------------------
__global__ __launch_bounds__(256) void proj_qkv(
    const short* __restrict__ qbf, const float* __restrict__ kin,
    const float* __restrict__ vin,
    const short* __restrict__ WqT, const short* __restrict__ WkT,
    const short* __restrict__ WvT,
    const float* __restrict__ bq, const float* __restrict__ bk,
    const float* __restrict__ bv,
    short* __restrict__ Qp, short* __restrict__ Kp, short* __restrict__ Vt)
{
    __shared__ short lA[2][64 * 64];
    __shared__ short lB[2][128 * 64];

    const int d   = blockIdx.x;      // 0..1279 = 8 XCDs x 160
    const int xcd = d & 7;
    const int idx = d >> 3;          // 0..159

    const int tid  = threadIdx.x;
    const int lane = tid & 63;
    const int wid  = tid >> 6;
    const int l16  = lane & 15;
    const int quad = lane >> 4;

    // gld16 chunk: 1KB = 8 rows x 128B. Lane i lands at (row=c*8+(i>>3),
    // granule=i&7); fetch global granule (i&7)^(i>>3) so LDS[row][g] holds
    // global[row][g ^ (row&7)].
    const int crow = lane >> 3;
    const int ccol = ((lane & 7) ^ crow) << 3;

    if (idx < 96) {
        // ----------------- Q path -----------------
        const int qo = xcd * 96 + idx;       // 0..767, bm-major
        const int y  = qo % 6;
        const int bm = qo / 6;               // A-panel id; sharers adjacent
        const short* WT = WqT + (size_t)y * 128 * DMODEL;
        const int wm = wid & 1;
        const int wn = wid >> 1;

        v4f acc[2][4];
#pragma unroll
        for (int i = 0; i < 2; ++i)
#pragma unroll
            for (int j = 0; j < 4; ++j) acc[i][j] = (v4f){0.f, 0.f, 0.f, 0.f};

        const short* Abase = qbf + (size_t)bm * 64 * DMODEL;

        auto stage = [&](int kt, int pb) {
#pragma unroll
            for (int c = wid; c < 8; c += 4)
                gld16(Abase + (size_t)(c * 8 + crow) * DMODEL + kt * 64 + ccol, &lA[pb][c * 512]);
#pragma unroll
            for (int c = wid; c < 16; c += 4)
                gld16(WT + (size_t)(c * 8 + crow) * DMODEL + kt * 64 + ccol, &lB[pb][c * 512]);
        };
        auto compute = [&](int cur) {
#pragma unroll
            for (int kk = 0; kk < 2; ++kk) {
                const int fcol = (((kk << 2) + quad) ^ (l16 & 7)) << 3;
                v8s af[2], bf[4];
#pragma unroll
                for (int i = 0; i < 2; ++i)
                    af[i] = *reinterpret_cast<const v8s*>(&lA[cur][(wm * 32 + i * 16 + l16) * 64 + fcol]);
#pragma unroll
                for (int j = 0; j < 4; ++j)
                    bf[j] = *reinterpret_cast<const v8s*>(&lB[cur][(wn * 64 + j * 16 + l16) * 64 + fcol]);
                __builtin_amdgcn_s_setprio(1);
#pragma unroll
                for (int i = 0; i < 2; ++i)
#pragma unroll
                    for (int j = 0; j < 4; ++j)
                        acc[i][j] = __builtin_amdgcn_mfma_f32_16x16x32_bf16(bf[j], af[i], acc[i][j], 0, 0, 0);
                __builtin_amdgcn_s_setprio(0);
            }
        };

        stage(0, 0);
        WAIT_VM0();
        BARRIER();
        for (int kt = 0; kt < 12; ++kt) {
            const int cur = kt & 1;
            if (kt < 11) stage(kt + 1, cur ^ 1);
            compute(cur);
            WAIT_VM0();
            BARRIER();
        }

        // epilogue: col=lane&15 = s (af idx); row=quad*4+reg = output col d
#pragma unroll
        for (int i = 0; i < 2; ++i) {
            const int s = bm * 64 + wm * 32 + i * 16 + l16;
            const int b = s >> 11, srow = s & 2047;
#pragma unroll
            for (int j = 0; j < 4; ++j) {
                const int C = y * 128 + wn * 64 + j * 16 + quad * 4;
                const int h = C >> 6, dd = C & 63;
                const float4 bb = *reinterpret_cast<const float4*>(&bq[C]);
                v4s p;
#pragma unroll
                for (int reg = 0; reg < 4; ++reg)
                    p[reg] = f2bs((acc[i][j][reg] + (&bb.x)[reg]) * LOG2E);
                *reinterpret_cast<v4s*>(
                    &Qp[((size_t)(b * HEADS + h) * SEQ + srow) * DK + dd]) = p;
            }
        }
    } else {
        // ----------------- K/V path -----------------
        const int kvo = xcd * 64 + (idx - 96);   // 0..511
        const int yv = kvo >> 8;                 // 0=K 1=V
        const int bm = kvo & 255;
        const float* A = yv ? vin : kin;
        const short* WT = yv ? WvT : WkT;

        v4f acc[2][2];
#pragma unroll
        for (int i = 0; i < 2; ++i)
#pragma unroll
            for (int j = 0; j < 2; ++j) acc[i][j] = (v4f){0.f, 0.f, 0.f, 0.f};

        float4 areg[2];

        auto loadA = [&](int kt) {
#pragma unroll
            for (int r = 0; r < 2; ++r) {
                const int f4 = tid + 256 * r;
                const int row = f4 >> 4;
                const int q4 = f4 & 15;
                areg[r] = *reinterpret_cast<const float4*>(
                    A + (size_t)(bm * 32 + row) * DMODEL + kt * 64 + q4 * 4);
            }
        };
        auto writeA = [&](int pb) {
#pragma unroll
            for (int r = 0; r < 2; ++r) {
                const int f4 = tid + 256 * r;
                const int row = f4 >> 4;
                const int q4 = f4 & 15;
                const int gran = q4 >> 1, half = q4 & 1;
                const int scol = ((gran ^ (row & 7)) << 3) + (half << 2);
                s4pack p{f2bs(areg[r].x), f2bs(areg[r].y), f2bs(areg[r].z), f2bs(areg[r].w)};
                *reinterpret_cast<s4pack*>(&lA[pb][row * 64 + scol]) = p;
            }
        };
        auto stageB = [&](int kt, int pb) {
#pragma unroll
            for (int c = wid; c < 16; c += 4)
                gld16(WT + (size_t)(c * 8 + crow) * DMODEL + kt * 64 + ccol, &lB[pb][c * 512]);
        };
        auto compute = [&](int cur) {
#pragma unroll
            for (int kk = 0; kk < 2; ++kk) {
                const int fcol = (((kk << 2) + quad) ^ (l16 & 7)) << 3;
                v8s af[2], bf[2];
#pragma unroll
                for (int i = 0; i < 2; ++i)
                    af[i] = *reinterpret_cast<const v8s*>(&lA[cur][(i * 16 + l16) * 64 + fcol]);
#pragma unroll
                for (int j = 0; j < 2; ++j)
                    bf[j] = *reinterpret_cast<const v8s*>(&lB[cur][(wid * 32 + j * 16 + l16) * 64 + fcol]);
                __builtin_amdgcn_s_setprio(1);
#pragma unroll
                for (int i = 0; i < 2; ++i)
#pragma unroll
                    for (int j = 0; j < 2; ++j) {
                        if (yv == 0)
                            acc[i][j] = __builtin_amdgcn_mfma_f32_16x16x32_bf16(bf[j], af[i], acc[i][j], 0, 0, 0);
                        else
                            acc[i][j] = __builtin_amdgcn_mfma_f32_16x16x32_bf16(af[i], bf[j], acc[i][j], 0, 0, 0);
                    }
                __builtin_amdgcn_s_setprio(0);
            }
        };

        loadA(0);
        writeA(0);
        stageB(0, 0);
        WAIT_VM0_LGKM0();
        BARRIER();
        for (int kt = 0; kt < 12; ++kt) {
            const int cur = kt & 1;
            if (kt < 11) { loadA(kt + 1); stageB(kt + 1, cur ^ 1); }
            compute(cur);
            if (kt < 11) writeA(cur ^ 1);
            WAIT_VM0_LGKM0();
            BARRIER();
        }

        if (yv == 0) {
            // K: swapped -> 4 regs = 4 consecutive d at fixed s
#pragma unroll
            for (int i = 0; i < 2; ++i) {
                const int s = bm * 32 + i * 16 + l16;
                const int b = s >> 11, srow = s & 2047;
#pragma unroll
                for (int j = 0; j < 2; ++j) {
                    const int Cl = wid * 32 + j * 16 + quad * 4;
                    const int g = Cl >> 6, dd = Cl & 63;
                    const float4 bb = *reinterpret_cast<const float4*>(&bk[Cl]);
                    v4s p;
#pragma unroll
                    for (int reg = 0; reg < 4; ++reg)
                        p[reg] = f2bs(acc[i][j][reg] + (&bb.x)[reg]);
                    *reinterpret_cast<v4s*>(
                        &Kp[((size_t)(b * GROUPS + g) * SEQ + srow) * DK + dd]) = p;
                }
            }
        } else {
            // V: non-swapped -> 4 regs = 4 consecutive s -> consecutive s2
#pragma unroll
            for (int j = 0; j < 2; ++j) {
                const int Cl = wid * 32 + j * 16 + l16;
                const int g = Cl >> 6, dd = Cl & 63;
                const float bvv = bv[Cl];
#pragma unroll
                for (int i = 0; i < 2; ++i) {
                    const int s = bm * 32 + i * 16 + quad * 4;   // reg=0 base
                    const int b = s >> 11, s0 = s & 2047;
                    const int s2 = (s0 & ~63) | (s0 & 0x23) | ((s0 & 0x0C) << 1) | ((s0 & 0x10) >> 2);
                    v4s p;
#pragma unroll
                    for (int reg = 0; reg < 4; ++reg)
                        p[reg] = f2bs(acc[i][j][reg] + bvv);
                    *reinterpret_cast<v4s*>(
                        &Vt[((size_t)(b * GROUPS + g) * DK + dd) * SEQ + s2]) = p;
                }
            }
        }
    }
}

// ---------------------------------------------------------------------------
// Flash attention: R1/R4 measured-best structure (66.5us) — unchanged.
// ---------------------------------------------------------------------------
__global__ __launch_bounds__(256) void attn_kernel(
    const short* __restrict__ Qp, const short* __restrict__ Kp,
    const short* __restrict__ Vt, short* __restrict__ Oat)
{
    const int LSK = 72;
    const int LSV = 136;
    __shared__ short lK[128 * 72];
    __shared__ short lV[64 * 136];

    const int qt = blockIdx.x, h = blockIdx.y, b = blockIdx.z;
    const int g = h & 1;
    const int tid  = threadIdx.x;
    const int lane = tid & 63;
    const int wid  = tid >> 6;
    const int l16  = lane & 15;
    const int quad = lane >> 4;

    v8s qf[2][2];
#pragma unroll
    for (int mi = 0; mi < 2; ++mi) {
        const size_t qbase =
            ((size_t)(b * HEADS + h) * SEQ + qt * 128 + wid * 32 + mi * 16 + l16) * DK;
        qf[mi][0] = *reinterpret_cast<const v8s*>(Qp + qbase + quad * 8);
        qf[mi][1] = *reinterpret_cast<const v8s*>(Qp + qbase + quad * 8 + 32);
    }

    const size_t kbase = (size_t)(b * GROUPS + g) * SEQ * DK;
    const size_t vbase = (size_t)(b * GROUPS + g) * DK * SEQ;

    const short one = (short)0x3F80;
    const v8s ones8 = {one, one, one, one, one, one, one, one};

    v4f oacc[2][5];
#pragma unroll
    for (int mi = 0; mi < 2; ++mi)
#pragma unroll
        for (int n = 0; n < 5; ++n) oacc[mi][n] = (v4f){0.f, 0.f, 0.f, 0.f};

    v8s kreg[4], vreg[4];

    auto issue_loads = [&](int kt) {
#pragma unroll
        for (int r = 0; r < 4; ++r) {
            const int idx = tid + 256 * r;
            const int rowK = idx >> 3, cK = (idx & 7) << 3;
            kreg[r] = *reinterpret_cast<const v8s*>(
                Kp + kbase + (size_t)(kt * 128 + rowK) * DK + cK);
            const int rowV = idx >> 4, cV = (idx & 15) << 3;
            vreg[r] = *reinterpret_cast<const v8s*>(
                Vt + vbase + (size_t)rowV * SEQ + kt * 128 + cV);
        }
    };
    auto write_lds = [&]() {
#pragma unroll
        for (int r = 0; r < 4; ++r) {
            const int idx = tid + 256 * r;
            const int rowK = idx >> 3, cK = (idx & 7) << 3;
            *reinterpret_cast<v8s*>(&lK[rowK * LSK + cK]) = kreg[r];
            const int rowV = idx >> 4, cV = (idx & 15) << 3;
            *reinterpret_cast<v8s*>(&lV[rowV * LSV + cV]) = vreg[r];
        }
    };

    issue_loads(0);
    for (int kt = 0; kt < 16; ++kt) {
        if (kt) BARRIER();            // readers of tile kt-1 done (no vmcnt drain)
        write_lds();                  // consumes kreg/vreg (compiler vmcnt waits)
        if (kt < 15) issue_loads(kt + 1);  // in flight across barrier + compute
        WAIT_LGKM0();                 // ds_writes visible before barrier
        BARRIER();

#pragma unroll
        for (int kt2 = 0; kt2 < 2; ++kt2) {
            v4s pp[2][4];
#pragma unroll
            for (int j = 0; j < 4; ++j) {
                const v8s kf0 = *reinterpret_cast<const v8s*>(
                    &lK[(kt2 * 64 + j * 16 + l16) * LSK + quad * 8]);
                const v8s kf1 = *reinterpret_cast<const v8s*>(
                    &lK[(kt2 * 64 + j * 16 + l16) * LSK + quad * 8 + 32]);
#pragma unroll
                for (int mi = 0; mi < 2; ++mi) {
                    v4f z = (v4f){0.f, 0.f, 0.f, 0.f};
                    __builtin_amdgcn_s_setprio(1);
                    z = __builtin_amdgcn_mfma_f32_16x16x32_bf16(kf0, qf[mi][0], z, 0, 0, 0);
                    z = __builtin_amdgcn_mfma_f32_16x16x32_bf16(kf1, qf[mi][1], z, 0, 0, 0);
                    __builtin_amdgcn_s_setprio(0);
                    v4s p;
#pragma unroll
                    for (int reg = 0; reg < 4; ++reg) p[reg] = f2bs(fast_exp2(z[reg]));
                    pp[mi][j] = p;
                }
            }

#pragma unroll
            for (int cj = 0; cj < 2; ++cj) {
                v8s pf[2];
#pragma unroll
                for (int mi = 0; mi < 2; ++mi)
                    pf[mi] = __builtin_shufflevector(pp[mi][2 * cj], pp[mi][2 * cj + 1],
                                                     0, 1, 2, 3, 4, 5, 6, 7);
                __builtin_amdgcn_s_setprio(1);
#pragma unroll
                for (int n = 0; n < 4; ++n) {
                    const v8s vf = *reinterpret_cast<const v8s*>(
                        &lV[(n * 16 + l16) * LSV + kt2 * 64 + cj * 32 + quad * 8]);
#pragma unroll
                    for (int mi = 0; mi < 2; ++mi)
                        oacc[mi][n] = __builtin_amdgcn_mfma_f32_16x16x32_bf16(pf[mi], vf, oacc[mi][n], 0, 0, 0);
                }
#pragma unroll
                for (int mi = 0; mi < 2; ++mi)
                    oacc[mi][4] = __builtin_amdgcn_mfma_f32_16x16x32_bf16(pf[mi], ones8, oacc[mi][4], 0, 0, 0);
                __builtin_amdgcn_s_setprio(0);
            }
        }
    }

#pragma unroll
    for (int mi = 0; mi < 2; ++mi) {
        float rdiv[4];
#pragma unroll
        for (int reg = 0; reg < 4; ++reg)
            rdiv[reg] = __builtin_amdgcn_rcpf(oacc[mi][4][reg]);
#pragma unroll
        for (int n = 0; n < 4; ++n)
#pragma unroll
            for (int reg = 0; reg < 4; ++reg) {
                const int qrow = qt * 128 + wid * 32 + mi * 16 + quad * 4 + reg;
                Oat[(size_t)(b * SEQ + qrow) * DMODEL + h * 64 + n * 16 + l16] =
                    f2bs(oacc[mi][n][reg] * rdiv[reg]);
            }
    }
}

// ---------------------------------------------------------------------------
// Output GEMM: BM=64, BN=128, BK=64, dbuf, R2 single-barrier loop, swizzle,
// float4 epilogue. XCD-chunked remap: o = bm*6+bn so the 6 bn-slices sharing
// one Oat A-panel run adjacently on one XCD. grid 768 (1D).
// ---------------------------------------------------------------------------
__global__ __launch_bounds__(256) void out_gemm(
    const short* __restrict__ A, const short* __restrict__ WT,
    const float* __restrict__ bias, float* __restrict__ out)
{
    __shared__ short lA[2][64 * 64];
    __shared__ short lB[2][128 * 64];

    const int d  = blockIdx.x;               // 0..767 = 8 XCDs x 96
    const int o  = (d & 7) * 96 + (d >> 3);  // bm-major order per XCD
    const int bn = o % 6;
    const int bm = o / 6;

    const int tid  = threadIdx.x;
    const int lane = tid & 63;
    const int wid  = tid >> 6;
    const int l16  = lane & 15;
    const int quad = lane >> 4;
    const int wm   = wid & 1;
    const int wn   = wid >> 1;

    v4f acc[2][4];
#pragma unroll
    for (int i = 0; i < 2; ++i)
#pragma unroll
        for (int j = 0; j < 4; ++j) acc[i][j] = (v4f){0.f, 0.f, 0.f, 0.f};

    const int crow = lane >> 3;
    const int ccol = ((lane & 7) ^ crow) << 3;
    const short* Abase = A + (size_t)bm * 64 * DMODEL;
    const short* Bbase = WT + (size_t)bn * 128 * DMODEL;

    auto stage = [&](int kt, int pb) {
#pragma unroll
        for (int c = wid; c < 8; c += 4)
            gld16(Abase + (size_t)(c * 8 + crow) * DMODEL + kt * 64 + ccol, &lA[pb][c * 512]);
#pragma unroll
        for (int c = wid; c < 16; c += 4)
            gld16(Bbase + (size_t)(c * 8 + crow) * DMODEL + kt * 64 + ccol, &lB[pb][c * 512]);
    };
    auto compute = [&](int cur) {
#pragma unroll
        for (int kk = 0; kk < 2; ++kk) {
            const int fcol = (((kk << 2) + quad) ^ (l16 & 7)) << 3;
            v8s af[2], bf[4];
#pragma unroll
            for (int i = 0; i < 2; ++i)
                af[i] = *reinterpret_cast<const v8s*>(&lA[cur][(wm * 32 + i * 16 + l16) * 64 + fcol]);
#pragma unroll
            for (int j = 0; j < 4; ++j)
                bf[j] = *reinterpret_cast<const v8s*>(&lB[cur][(wn * 64 + j * 16 + l16) * 64 + fcol]);
            __builtin_amdgcn_s_setprio(1);
#pragma unroll
            for (int i = 0; i < 2; ++i)
#pragma unroll
                for (int j = 0; j < 4; ++j)
                    acc[i][j] = __builtin_amdgcn_mfma_f32_16x16x32_bf16(bf[j], af[i], acc[i][j], 0, 0, 0);
            __builtin_amdgcn_s_setprio(0);
        }
    };

    stage(0, 0);
    WAIT_VM0();
    BARRIER();
    for (int kt = 0; kt < 12; ++kt) {
        const int cur = kt & 1;
        if (kt < 11) stage(kt + 1, cur ^ 1);
        compute(cur);
        WAIT_VM0();
        BARRIER();
    }

    // epilogue: col=lane&15 = R row; row=quad*4+reg = C col -> float4 store
#pragma unroll
    for (int i = 0; i < 2; ++i) {
        const int R = bm * 64 + wm * 32 + i * 16 + l16;
#pragma unroll
        for (int j = 0; j < 4; ++j) {
            const int C = bn * 128 + wn * 64 + j * 16 + quad * 4;
            const float4 bb = *reinterpret_cast<const float4*>(&bias[C]);
            float4 oo;
#pragma unroll
            for (int reg = 0; reg < 4; ++reg)
                (&oo.x)[reg] = acc[i][j][reg] + (&bb.x)[reg];
            *reinterpret_cast<float4*>(&out[(size_t)R * DMODEL + C]) = oo;
        }
    }
}

extern "C" void kernel_launch(void* const* d_in, const int* in_sizes, int n_in,
                              void* d_out, int out_size, void* d_ws, size_t ws_size,
                              hipStream_t stream) {
    const float* q  = (const float*)d_in[0];
    const float* k  = (const float*)d_in[1];
    const float* v  = (const float*)d_in[2];
    const float* Wq = (const float*)d_in[3];
    const float* bq = (const float*)d_in[4];
    const float* Wk = (const float*)d_in[5];
    const float* bk = (const float*)d_in[6];
    const float* Wv = (const float*)d_in[7];
    const float* bv = (const float*)d_in[8];
    const float* Wo = (const float*)d_in[9];
    const float* bo = (const float*)d_in[10];

    short* WqT = (short*)d_ws;                              // 589824
    short* WkT = WqT + 589824;                              // 98304
    short* WvT = WkT + 98304;                               // 98304
    short* WoT = WvT + 98304;                               // 589824
    short* qbf = WoT + 589824;                              // 6291456
    short* Qp  = qbf + 6291456;                             // [b,h,s,d]  6291456
    short* Kp  = Qp + (size_t)BS * HEADS * SEQ * DK;        // [b,g,s,d]  1048576
    short* Vt  = Kp + (size_t)BS * GROUPS * SEQ * DK;       // [b,g,d,s_perm] 1048576
    short* Oat = Vt + (size_t)BS * GROUPS * SEQ * DK;       // [b,s,h*d]  6291456

    prep<<<2880, 256, 0, stream>>>(q, Wq, Wk, Wv, Wo, qbf, WqT, WkT, WvT, WoT);
    proj_qkv<<<1280, 256, 0, stream>>>(qbf, k, v, WqT, WkT, WvT,
                                       bq, bk, bv, Qp, Kp, Vt);
    attn_kernel<<<dim3(16, HEADS, BS), 256, 0, stream>>>(Qp, Kp, Vt, Oat);
    out_gemm<<<768, 256, 0, stream>>>(Oat, WoT, bo, (float*)d_out);
}